// Round 1
// baseline (82.013 us; speedup 1.0000x reference)
//
#include <hip/hip_runtime.h>
#include <hip/hip_bf16.h>

// Rx_layer: apply Rx(w)^{⊗12} to 512 complex state vectors of length 4096.
// Kron power of identical 2x2 gates == 12 per-bit butterfly passes:
//   new0 = a*s0 - i b*s1 ; new1 = a*s1 - i b*s0, a=cos(w/2), b=sin(w/2)
// One block per state vector; vector staged in LDS (32 KB), 12 stages.

#define DIM 4096
#define NQ 12
#define TPB 256

template <bool INTERLEAVED>
__global__ __launch_bounds__(TPB) void rx_layer_kernel(
    const float* __restrict__ re, const float* __restrict__ im,
    const float* __restrict__ w, float* __restrict__ out)
{
    __shared__ float sre[DIM];
    __shared__ float sim[DIM];

    const int v   = blockIdx.x;
    const int tid = threadIdx.x;

    // ---- load: float4-coalesced global -> LDS ----
    const float4* re4 = (const float4*)(re + (size_t)v * DIM);
    const float4* im4 = (const float4*)(im + (size_t)v * DIM);
    float4* sre4 = (float4*)sre;
    float4* sim4 = (float4*)sim;
#pragma unroll
    for (int i = tid; i < DIM / 4; i += TPB) {
        sre4[i] = re4[i];
        sim4[i] = im4[i];
    }

    const float half = 0.5f * w[0];
    float ca, sb;
    __sincosf(half, &sb, &ca);   // fast approx is plenty (threshold 0.103)
    // refine with precise versions (cheap, once per thread)
    ca = cosf(half);
    sb = sinf(half);

    __syncthreads();

    // ---- 12 butterfly stages over LDS ----
#pragma unroll
    for (int q = 0; q < NQ; ++q) {
        const int bit  = 1 << q;
        const int mask = bit - 1;
#pragma unroll
        for (int p = tid; p < DIM / 2; p += TPB) {
            const int i0 = ((p & ~mask) << 1) | (p & mask);
            const int i1 = i0 | bit;
            const float r0 = sre[i0], m0 = sim[i0];
            const float r1 = sre[i1], m1 = sim[i1];
            sre[i0] = ca * r0 + sb * m1;
            sim[i0] = ca * m0 - sb * r1;
            sre[i1] = ca * r1 + sb * m0;
            sim[i1] = ca * m1 - sb * r0;
        }
        __syncthreads();
    }

    // ---- store ----
    if (INTERLEAVED) {
        // complex64 viewed as float32 pairs (re, im)
        float4* o4 = (float4*)(out + (size_t)v * DIM * 2);
#pragma unroll
        for (int j = tid; j < DIM / 2; j += TPB) {
            const int k = 2 * j;
            o4[j] = make_float4(sre[k], sim[k], sre[k + 1], sim[k + 1]);
        }
    } else {
        // harness stores the real part only (complex64 -> float32 cast)
        float4* o4 = (float4*)(out + (size_t)v * DIM);
#pragma unroll
        for (int i = tid; i < DIM / 4; i += TPB) {
            o4[i] = sre4[i];
        }
    }
}

extern "C" void kernel_launch(void* const* d_in, const int* in_sizes, int n_in,
                              void* d_out, int out_size, void* d_ws, size_t ws_size,
                              hipStream_t stream)
{
    const float* re = (const float*)d_in[0];
    const float* im = (const float*)d_in[1];
    const float* w  = (const float*)d_in[2];
    float* out = (float*)d_out;

    const int nvec = in_sizes[0] / DIM;  // B*BLK*DC = 512

    if (out_size == 2 * in_sizes[0]) {
        // interleaved complex output
        rx_layer_kernel<true><<<nvec, TPB, 0, stream>>>(re, im, w, out);
    } else {
        // real-part-only output
        rx_layer_kernel<false><<<nvec, TPB, 0, stream>>>(re, im, w, out);
    }
}

// Round 2
// 76.199 us; speedup vs baseline: 1.0763x; 1.0763x over previous
//
#include <hip/hip_runtime.h>
#include <hip/hip_bf16.h>

// Rx_layer: apply Rx(w)^{⊗12} to 512 complex state vectors of length 4096.
//
// Ownership: thread t (0..255) of block v owns elements j = 1024*h + 4*t + c,
// h,c in 0..3  (16 complex = 32 VGPRs).
//   bits 0,1   (c)        -> register butterflies
//   bits 2..7  (lane 0..5)-> __shfl_xor butterflies (uniform formula:
//                            new_r = a*r + b*shfl(im); new_im = a*im - b*shfl(r))
//   bits 8,9   (wave id)  -> single LDS exchange, 4x4 combine with
//                            Rx⊗Rx = a^2 I - i a b (I⊗X + X⊗I) - b^2 (X⊗X)
//   bits 10,11 (h)        -> register butterflies
// Exactly one __syncthreads per block.

#define DIM 4096
#define TPB 256

__device__ __forceinline__ void bf(float ca, float sb,
                                   float& r0, float& q0, float& r1, float& q1)
{
    const float nr0 = ca * r0 + sb * q1;
    const float nq0 = ca * q0 - sb * r1;
    const float nr1 = ca * r1 + sb * q0;
    const float nq1 = ca * q1 - sb * r0;
    r0 = nr0; q0 = nq0; r1 = nr1; q1 = nq1;
}

template <bool INTERLEAVED>
__global__ __launch_bounds__(TPB) void rx_layer_kernel(
    const float* __restrict__ re, const float* __restrict__ im,
    const float* __restrict__ w, float* __restrict__ out)
{
    __shared__ float lds[32][TPB];   // [value k][thread t] -> lane-contiguous

    const int v = blockIdx.x;
    const int t = threadIdx.x;

    // ---- coalesced float4 loads: 16 complex per thread ----
    const float4* re4 = (const float4*)(re + (size_t)v * DIM);
    const float4* im4 = (const float4*)(im + (size_t)v * DIM);

    float r[4][4], q[4][4];
#pragma unroll
    for (int h = 0; h < 4; ++h) {
        const float4 a = re4[256 * h + t];
        const float4 b = im4[256 * h + t];
        r[h][0] = a.x; r[h][1] = a.y; r[h][2] = a.z; r[h][3] = a.w;
        q[h][0] = b.x; q[h][1] = b.y; q[h][2] = b.z; q[h][3] = b.w;
    }

    const float half = 0.5f * w[0];
    const float ca = cosf(half);
    const float sb = sinf(half);

    // ---- register stages: bits 0,1 (c) ----
#pragma unroll
    for (int h = 0; h < 4; ++h) {
        bf(ca, sb, r[h][0], q[h][0], r[h][1], q[h][1]);
        bf(ca, sb, r[h][2], q[h][2], r[h][3], q[h][3]);
        bf(ca, sb, r[h][0], q[h][0], r[h][2], q[h][2]);
        bf(ca, sb, r[h][1], q[h][1], r[h][3], q[h][3]);
    }
    // ---- register stages: bits 10,11 (h) ----
#pragma unroll
    for (int c = 0; c < 4; ++c) {
        bf(ca, sb, r[0][c], q[0][c], r[1][c], q[1][c]);
        bf(ca, sb, r[2][c], q[2][c], r[3][c], q[3][c]);
        bf(ca, sb, r[0][c], q[0][c], r[2][c], q[2][c]);
        bf(ca, sb, r[1][c], q[1][c], r[3][c], q[3][c]);
    }

    // ---- shuffle stages: element bits 2..7 = lane bits 0..5 ----
#pragma unroll
    for (int s = 0; s < 6; ++s) {
        const int m = 1 << s;
#pragma unroll
        for (int h = 0; h < 4; ++h)
#pragma unroll
            for (int c = 0; c < 4; ++c) {
                const float rp = __shfl_xor(r[h][c], m, 64);
                const float qp = __shfl_xor(q[h][c], m, 64);
                r[h][c] = ca * r[h][c] + sb * qp;
                q[h][c] = ca * q[h][c] - sb * rp;
            }
    }

    // ---- LDS one-shot combine: element bits 8,9 = wave bits 0,1 ----
    const int wv = t >> 6;
    const int l  = t & 63;
#pragma unroll
    for (int h = 0; h < 4; ++h)
#pragma unroll
        for (int c = 0; c < 4; ++c) {
            const int k = (h * 4 + c) * 2;
            lds[k + 0][t] = r[h][c];
            lds[k + 1][t] = q[h][c];
        }
    __syncthreads();

    const float A2 = ca * ca;
    const float AB = ca * sb;
    const float B2 = sb * sb;
    const int p1 = ((wv ^ 1) << 6) | l;
    const int p2 = ((wv ^ 2) << 6) | l;
    const int p3 = ((wv ^ 3) << 6) | l;

#pragma unroll
    for (int h = 0; h < 4; ++h)
#pragma unroll
        for (int c = 0; c < 4; ++c) {
            const int k = (h * 4 + c) * 2;
            const float r1 = lds[k][p1],     r2 = lds[k][p2],     r3 = lds[k][p3];
            const float q1 = lds[k + 1][p1], q2 = lds[k + 1][p2], q3 = lds[k + 1][p3];
            const float nr = A2 * r[h][c] + AB * (q1 + q2) - B2 * r3;
            const float nq = A2 * q[h][c] - AB * (r1 + r2) - B2 * q3;
            r[h][c] = nr;
            q[h][c] = nq;
        }

    // ---- store ----
    if (INTERLEAVED) {
        float* o = out + (size_t)v * DIM * 2;
#pragma unroll
        for (int h = 0; h < 4; ++h) {
            float4* o4 = (float4*)(o + 2048 * h + 8 * t);
            o4[0] = make_float4(r[h][0], q[h][0], r[h][1], q[h][1]);
            o4[1] = make_float4(r[h][2], q[h][2], r[h][3], q[h][3]);
        }
    } else {
        float4* o4 = (float4*)(out + (size_t)v * DIM);
#pragma unroll
        for (int h = 0; h < 4; ++h)
            o4[256 * h + t] = make_float4(r[h][0], r[h][1], r[h][2], r[h][3]);
    }
}

extern "C" void kernel_launch(void* const* d_in, const int* in_sizes, int n_in,
                              void* d_out, int out_size, void* d_ws, size_t ws_size,
                              hipStream_t stream)
{
    const float* re = (const float*)d_in[0];
    const float* im = (const float*)d_in[1];
    const float* w  = (const float*)d_in[2];
    float* out = (float*)d_out;

    const int nvec = in_sizes[0] / DIM;  // B*BLK*DC = 512

    if (out_size == 2 * in_sizes[0]) {
        rx_layer_kernel<true><<<nvec, TPB, 0, stream>>>(re, im, w, out);
    } else {
        rx_layer_kernel<false><<<nvec, TPB, 0, stream>>>(re, im, w, out);
    }
}

// Round 3
// 75.692 us; speedup vs baseline: 1.0835x; 1.0067x over previous
//
#include <hip/hip_runtime.h>
#include <hip/hip_bf16.h>

// Rx_layer: apply Rx(w)^{⊗12} to 512 complex state vectors of length 4096.
//
// Butterfly per bit k: new0 = a*s0 - i b*s1 ; new1 = a*s1 - i b*s0,
// a = cos(w/2), b = sin(w/2).  With s = r + i q:
//   r0' = a r0 + b q1 ; q0' = a q0 - b r1 ; r1' = a r1 + b q0 ; q1' = a q1 - b r0
//
// Structure (per block = one vector, 256 threads, 16 complex/thread):
//   Phase A: thread owns bits {0,1,10,11} (j = 1024h + 4t + c) -> 4 reg stages
//            (float4-coalesced global loads)
//   Exchange 1 (LDS buf0, float2 pairs, b64 ops): re-own bits {2,3,4,5} -> 4 stages
//   Exchange 2 (LDS buf1): re-own bits {6,7,8,9} -> 4 stages -> coalesced stores
// XOR swizzle sig(j) = j ^ ((j>>6)&15) makes every exchange pattern hit the
// b64 bank-throughput floor (16 distinct bank-pairs / 64 lanes / instruction).
// Exactly 2 barriers; 64 KB LDS (2 blocks/CU).

#define DIM 4096
#define TPB 256

__device__ __forceinline__ int sig(int j) { return j ^ ((j >> 6) & 15); }

__device__ __forceinline__ void bf(float ca, float sb,
                                   float& r0, float& q0, float& r1, float& q1)
{
    const float nr0 = ca * r0 + sb * q1;
    const float nq0 = ca * q0 - sb * r1;
    const float nr1 = ca * r1 + sb * q0;
    const float nq1 = ca * q1 - sb * r0;
    r0 = nr0; q0 = nq0; r1 = nr1; q1 = nq1;
}

template <bool INTERLEAVED>
__global__ __launch_bounds__(TPB) void rx_layer_kernel(
    const float* __restrict__ re, const float* __restrict__ im,
    const float* __restrict__ w, float* __restrict__ out)
{
    __shared__ float2 buf0[DIM];   // 32 KB
    __shared__ float2 buf1[DIM];   // 32 KB

    const int v = blockIdx.x;
    const int t = threadIdx.x;

    // ---- Phase A: coalesced float4 loads, owns j = 1024h + 4t + c ----
    const float4* re4 = (const float4*)(re + (size_t)v * DIM);
    const float4* im4 = (const float4*)(im + (size_t)v * DIM);

    float r[4][4], q[4][4];
#pragma unroll
    for (int h = 0; h < 4; ++h) {
        const float4 a = re4[256 * h + t];
        const float4 b = im4[256 * h + t];
        r[h][0] = a.x; r[h][1] = a.y; r[h][2] = a.z; r[h][3] = a.w;
        q[h][0] = b.x; q[h][1] = b.y; q[h][2] = b.z; q[h][3] = b.w;
    }

    const float half = 0.5f * w[0];
    const float ca = cosf(half);
    const float sb = sinf(half);

    // bits 0,1 (c)
#pragma unroll
    for (int h = 0; h < 4; ++h) {
        bf(ca, sb, r[h][0], q[h][0], r[h][1], q[h][1]);
        bf(ca, sb, r[h][2], q[h][2], r[h][3], q[h][3]);
        bf(ca, sb, r[h][0], q[h][0], r[h][2], q[h][2]);
        bf(ca, sb, r[h][1], q[h][1], r[h][3], q[h][3]);
    }
    // bits 10,11 (h)
#pragma unroll
    for (int c = 0; c < 4; ++c) {
        bf(ca, sb, r[0][c], q[0][c], r[1][c], q[1][c]);
        bf(ca, sb, r[2][c], q[2][c], r[3][c], q[3][c]);
        bf(ca, sb, r[0][c], q[0][c], r[2][c], q[2][c]);
        bf(ca, sb, r[1][c], q[1][c], r[3][c], q[3][c]);
    }

    // ---- Exchange 1: buf0, re-own bits {2,3,4,5} ----
#pragma unroll
    for (int h = 0; h < 4; ++h)
#pragma unroll
        for (int c = 0; c < 4; ++c)
            buf0[sig(1024 * h + 4 * t + c)] = make_float2(r[h][c], q[h][c]);
    __syncthreads();

    // phase B: j = (t7t6<<10) | (t5..t2<<6) | (e<<2) | t1t0
    const int baseB = ((t >> 6) << 10) | (((t >> 2) & 15) << 6) | (t & 3);
    float rb[16], qb[16];
#pragma unroll
    for (int e = 0; e < 16; ++e) {
        const float2 x = buf0[sig(baseB + (e << 2))];
        rb[e] = x.x; qb[e] = x.y;
    }
    // 4 stages on bits 2..5 (array index bits 0..3)
#pragma unroll
    for (int s = 0; s < 4; ++s) {
        const int m = 1 << s;
#pragma unroll
        for (int i = 0; i < 16; ++i)
            if (!(i & m))
                bf(ca, sb, rb[i], qb[i], rb[i | m], qb[i | m]);
    }

    // ---- Exchange 2: buf1, re-own bits {6,7,8,9} ----
#pragma unroll
    for (int e = 0; e < 16; ++e)
        buf1[sig(baseB + (e << 2))] = make_float2(rb[e], qb[e]);
    __syncthreads();

    // phase C: j = (t7t6<<10) | (f<<6) | (t5..t2<<2) | t1t0
    const int baseC = ((t >> 6) << 10) | (((t >> 2) & 15) << 2) | (t & 3);
    float rc[16], qc[16];
#pragma unroll
    for (int f = 0; f < 16; ++f) {
        const float2 x = buf1[sig(baseC + (f << 6))];
        rc[f] = x.x; qc[f] = x.y;
    }
    // 4 stages on bits 6..9 (array index bits 0..3)
#pragma unroll
    for (int s = 0; s < 4; ++s) {
        const int m = 1 << s;
#pragma unroll
        for (int i = 0; i < 16; ++i)
            if (!(i & m))
                bf(ca, sb, rc[i], qc[i], rc[i | m], qc[i | m]);
    }

    // ---- store (coalesced: lanes cover 64 consecutive j per instruction) ----
    if (INTERLEAVED) {
        float2* o2 = (float2*)out + (size_t)v * DIM;
#pragma unroll
        for (int f = 0; f < 16; ++f)
            o2[baseC + (f << 6)] = make_float2(rc[f], qc[f]);
    } else {
        float* o = out + (size_t)v * DIM + baseC;
#pragma unroll
        for (int f = 0; f < 16; ++f)
            o[f << 6] = rc[f];
    }
}

extern "C" void kernel_launch(void* const* d_in, const int* in_sizes, int n_in,
                              void* d_out, int out_size, void* d_ws, size_t ws_size,
                              hipStream_t stream)
{
    const float* re = (const float*)d_in[0];
    const float* im = (const float*)d_in[1];
    const float* w  = (const float*)d_in[2];
    float* out = (float*)d_out;

    const int nvec = in_sizes[0] / DIM;  // B*BLK*DC = 512

    if (out_size == 2 * in_sizes[0]) {
        rx_layer_kernel<true><<<nvec, TPB, 0, stream>>>(re, im, w, out);
    } else {
        rx_layer_kernel<false><<<nvec, TPB, 0, stream>>>(re, im, w, out);
    }
}